// Round 9
// baseline (560.387 us; speedup 1.0000x reference)
//
#include <hip/hip_runtime.h>
#include <math.h>

#define BATCH 1024
#define SEQ   200
#define DIN   128
#define DOUT  128
#define PSTR  608    // partial-delta row stride (floats): 600 data + 8 pad

// ---- K0: transpose S (64 KB, one-time) so both S and S^T are coalesced ----
__global__ __launch_bounds__(256) void k_transpose(const float* __restrict__ S,
                                                   float* __restrict__ ST) {
    int idx = blockIdx.x * 256 + threadIdx.x;   // 0..16383
    int d = idx >> 7, e = idx & 127;
    ST[e * DIN + d] = S[d * DOUT + e];
}

// ---- K_scan: softmax prefix tables. Logits v[k,l] are IDENTICAL for all b;
//      only mask length n_b differs. Per k, compute prefix max M[n] and
//      inverse denom iE[n] = 1/sum_{l<n} exp(v-M[n]) for n=1..200.
//      Then W[b,k,l] = exp(v[l]-M[n_b]) * iE[n_b]  (l<n_b), exactly the
//      reference's per-row masked softmax semantics. 3 blocks, ~2us. ----
__global__ __launch_bounds__(256) void k_scan(const float* __restrict__ Bm,
                                              const float* __restrict__ a0,
                                              const float* __restrict__ a1,
                                              float* __restrict__ v,
                                              float* __restrict__ Mn,
                                              float* __restrict__ iEn, int iter) {
    __shared__ float sv[SEQ];
    const int k = blockIdx.x, t = threadIdx.x;
    if (t < SEQ) {
        float x = Bm[k * SEQ + t];
        if (iter >= 1) x += a0[k * SEQ + t];
        if (iter >= 2) x += a1[k * SEQ + t];
        sv[t] = x;
        v[k * SEQ + t] = x;
    }
    __syncthreads();
    if (t < SEQ) {
        const int n = t + 1;           // thread computes prefix of length n
        float m = -INFINITY, s = 0.f;
        for (int l = 0; l < n; ++l) {  // LDS broadcast reads (lockstep l)
            float x = sv[l];
            float nm = fmaxf(m, x);
            s = s * expf(m - nm) + expf(x - nm);   // m=-inf: expf(-inf)=0, safe
            m = nm;
        }
        Mn[k * 201 + n] = m;
        iEn[k * 201 + n] = 1.f / s;
    }
}

// ---- K_wa: WA partials = W @ A. Pure streaming kernel: 2048 blocks
//      (b, half), 4 waves x 25 rows, 8-deep batches, ~56 VGPR -> 8 blocks/CU
//      = 32 waves/CU ALL in the A-stream simultaneously. ----
__global__ __launch_bounds__(256, 4) void k_wa(const float* __restrict__ A,
                                               const float* __restrict__ v,
                                               const float* __restrict__ Mn,
                                               const float* __restrict__ iEn,
                                               const int* __restrict__ seq,
                                               float* __restrict__ pw) {
    __shared__ float pB[4][3][DIN];
    const int t = threadIdx.x, lane = t & 63, w = t >> 6;
    const int b = blockIdx.x >> 1, half = blockIdx.x & 1;
    const int n = seq[b];
    const float2* a2 = (const float2*)(A + (size_t)b * (SEQ * DIN));
    const float M0 = Mn[n],       E0 = iEn[n];
    const float M1 = Mn[201 + n], E1 = iEn[201 + n];
    const float M2 = Mn[402 + n], E2 = iEn[402 + n];
    const int l0 = half * 100 + w * 25;
    float h00 = 0.f, h01 = 0.f, h10 = 0.f, h11 = 0.f, h20 = 0.f, h21 = 0.f;

#define WROW(L, V) { \
    float w0 = ((L) < n) ? expf(v[(L)] - M0) * E0 : 0.f;       \
    float w1 = ((L) < n) ? expf(v[200 + (L)] - M1) * E1 : 0.f; \
    float w2 = ((L) < n) ? expf(v[400 + (L)] - M2) * E2 : 0.f; \
    h00 = fmaf(w0, (V).x, h00); h01 = fmaf(w0, (V).y, h01);    \
    h10 = fmaf(w1, (V).x, h10); h11 = fmaf(w1, (V).y, h11);    \
    h20 = fmaf(w2, (V).x, h20); h21 = fmaf(w2, (V).y, h21); }

    for (int g = 0; g < 3; ++g) {      // 3 batches of 8 rows
        const int lb = l0 + g * 8;
        float2 v0 = a2[(size_t)(lb + 0) * 64 + lane];
        float2 v1 = a2[(size_t)(lb + 1) * 64 + lane];
        float2 v2 = a2[(size_t)(lb + 2) * 64 + lane];
        float2 v3 = a2[(size_t)(lb + 3) * 64 + lane];
        float2 v4 = a2[(size_t)(lb + 4) * 64 + lane];
        float2 v5 = a2[(size_t)(lb + 5) * 64 + lane];
        float2 v6 = a2[(size_t)(lb + 6) * 64 + lane];
        float2 v7 = a2[(size_t)(lb + 7) * 64 + lane];
        WROW(lb + 0, v0) WROW(lb + 1, v1) WROW(lb + 2, v2) WROW(lb + 3, v3)
        WROW(lb + 4, v4) WROW(lb + 5, v5) WROW(lb + 6, v6) WROW(lb + 7, v7)
    }
    {   // remainder row l0+24
        float2 v0 = a2[(size_t)(l0 + 24) * 64 + lane];
        WROW(l0 + 24, v0)
    }
#undef WROW

    pB[w][0][2 * lane] = h00; pB[w][0][2 * lane + 1] = h01;
    pB[w][1][2 * lane] = h10; pB[w][1][2 * lane + 1] = h11;
    pB[w][2][2 * lane] = h20; pB[w][2][2 * lane + 1] = h21;
    __syncthreads();
    if (t < DIN) {
        float* dst = pw + ((size_t)b * 2 + half) * 384;
        dst[t]       = pB[0][0][t] + pB[1][0][t] + pB[2][0][t] + pB[3][0][t];
        dst[128 + t] = pB[0][1][t] + pB[1][1][t] + pB[2][1][t] + pB[3][1][t];
        dst[256 + t] = pB[0][2][t] + pB[1][2][t] + pB[2][2][t] + pB[3][2][t];
    }
}

// ---- K_mid: WA -> high -> hS. All-L2 kernel, 1024 blocks. ----
__global__ __launch_bounds__(256) void k_mid(const float* __restrict__ pw,
                                             const float* __restrict__ S,
                                             const float* __restrict__ ST,
                                             float* __restrict__ hs,
                                             float* __restrict__ out, int iter) {
    __shared__ float sWA[3][DIN];
    __shared__ float pb2[2][3][DIN];
    __shared__ float sH[3][DIN];
    const int t = threadIdx.x, b = blockIdx.x;
    const float* p0 = pw + (size_t)b * 2 * 384;
    if (t < DIN) {
        sWA[0][t] = p0[t]       + p0[384 + t];
        sWA[1][t] = p0[128 + t] + p0[384 + 128 + t];
        sWA[2][t] = p0[256 + t] + p0[384 + 256 + t];
    }
    __syncthreads();

    // high_raw = WA @ S : e = t&127, hh = d-half; 8x8 named batches (L2-hot)
    {
        const int e = t & 127, hh = t >> 7;
        const float* Scol = S + e;
        float g0 = 0.f, g1 = 0.f, g2 = 0.f;
        for (int g = 0; g < 8; ++g) {
            const int db = hh * 64 + g * 8;
            float s0 = Scol[(db + 0) * DOUT];
            float s1 = Scol[(db + 1) * DOUT];
            float s2 = Scol[(db + 2) * DOUT];
            float s3 = Scol[(db + 3) * DOUT];
            float s4 = Scol[(db + 4) * DOUT];
            float s5 = Scol[(db + 5) * DOUT];
            float s6 = Scol[(db + 6) * DOUT];
            float s7 = Scol[(db + 7) * DOUT];
#define HB_FMA(J, SV) \
            g0 = fmaf(sWA[0][db + J], SV, g0); \
            g1 = fmaf(sWA[1][db + J], SV, g1); \
            g2 = fmaf(sWA[2][db + J], SV, g2);
            HB_FMA(0, s0) HB_FMA(1, s1) HB_FMA(2, s2) HB_FMA(3, s3)
            HB_FMA(4, s4) HB_FMA(5, s5) HB_FMA(6, s6) HB_FMA(7, s7)
#undef HB_FMA
        }
        pb2[hh][0][e] = g0; pb2[hh][1][e] = g1; pb2[hh][2][e] = g2;
    }
    __syncthreads();

    // combine halves + squash; write out on last iter
    if (t < DIN) {
        float g0 = pb2[0][0][t] + pb2[1][0][t];
        float g1 = pb2[0][1][t] + pb2[1][1][t];
        float g2 = pb2[0][2][t] + pb2[1][2][t];
        float sq = g0 * g0 + g1 * g1 + g2 * g2;
        float scale = sq / (1.f + sq) / sqrtf(sq + 1e-9f);
        g0 *= scale; g1 *= scale; g2 *= scale;
        if (iter == 2) {
            size_t o = (size_t)b * 3 * DOUT + t;
            out[o] = g0; out[o + DOUT] = g1; out[o + 2 * DOUT] = g2;
        } else {
            sH[0][t] = g0; sH[1][t] = g1; sH[2][t] = g2;
        }
    }
    if (iter == 2) return;   // uniform exit
    __syncthreads();

    // hS = high @ S^T : d = t&127, hh = e-half; 8x8 named batches
    {
        const int d = t & 127, hh = t >> 7;
        const float* STcol = ST + d;
        float s0a = 0.f, s1a = 0.f, s2a = 0.f;
        for (int g = 0; g < 8; ++g) {
            const int eb = hh * 64 + g * 8;
            float s0 = STcol[(eb + 0) * DIN];
            float s1 = STcol[(eb + 1) * DIN];
            float s2 = STcol[(eb + 2) * DIN];
            float s3 = STcol[(eb + 3) * DIN];
            float s4 = STcol[(eb + 4) * DIN];
            float s5 = STcol[(eb + 5) * DIN];
            float s6 = STcol[(eb + 6) * DIN];
            float s7 = STcol[(eb + 7) * DIN];
#define HS_FMA(J, SV) \
            s0a = fmaf(sH[0][eb + J], SV, s0a); \
            s1a = fmaf(sH[1][eb + J], SV, s1a); \
            s2a = fmaf(sH[2][eb + J], SV, s2a);
            HS_FMA(0, s0) HS_FMA(1, s1) HS_FMA(2, s2) HS_FMA(3, s3)
            HS_FMA(4, s4) HS_FMA(5, s5) HS_FMA(6, s6) HS_FMA(7, s7)
#undef HS_FMA
        }
        pb2[hh][0][d] = s0a; pb2[hh][1][d] = s1a; pb2[hh][2][d] = s2a;
    }
    __syncthreads();
    if (t < DIN) {
        float* dst = hs + (size_t)b * 384;
        dst[t]       = pb2[0][0][t] + pb2[1][0][t];
        dst[128 + t] = pb2[0][1][t] + pb2[1][1][t];
        dst[256 + t] = pb2[0][2][t] + pb2[1][2][t];
    }
}

// ---- K_pc: B_delta partials = hS @ A^T. 1024 blocks, thread = row gather
//      (line-efficient: each A byte read once, L1 serves the 4x j-reuse). ----
__global__ __launch_bounds__(256, 2) void k_pc(const float* __restrict__ A,
                                               const float* __restrict__ hs,
                                               float* __restrict__ part) {
    const int t = threadIdx.x, b = blockIdx.x;
    if (t >= SEQ) return;
    const float* row = A + (size_t)b * (SEQ * DIN) + (size_t)t * DIN;
    const float* h = hs + (size_t)b * 384;
    float d0 = 0.f, d1 = 0.f, d2 = 0.f;
    for (int g = 0; g < 4; ++g) {
        const int jb = g * 8;
        float4 u0 = *(const float4*)&row[4 * (jb + 0)];
        float4 u1 = *(const float4*)&row[4 * (jb + 1)];
        float4 u2 = *(const float4*)&row[4 * (jb + 2)];
        float4 u3 = *(const float4*)&row[4 * (jb + 3)];
        float4 u4 = *(const float4*)&row[4 * (jb + 4)];
        float4 u5 = *(const float4*)&row[4 * (jb + 5)];
        float4 u6 = *(const float4*)&row[4 * (jb + 6)];
        float4 u7 = *(const float4*)&row[4 * (jb + 7)];
#define PC_FMA(J, U) { \
        float4 x0 = *(const float4*)&h[4 * (jb + J)];       \
        float4 x1 = *(const float4*)&h[128 + 4 * (jb + J)]; \
        float4 x2 = *(const float4*)&h[256 + 4 * (jb + J)]; \
        d0 += x0.x * U.x + x0.y * U.y + x0.z * U.z + x0.w * U.w; \
        d1 += x1.x * U.x + x1.y * U.y + x1.z * U.z + x1.w * U.w; \
        d2 += x2.x * U.x + x2.y * U.y + x2.z * U.z + x2.w * U.w; }
        PC_FMA(0, u0) PC_FMA(1, u1) PC_FMA(2, u2) PC_FMA(3, u3)
        PC_FMA(4, u4) PC_FMA(5, u5) PC_FMA(6, u6) PC_FMA(7, u7)
#undef PC_FMA
    }
    float* pp = part + (size_t)b * PSTR;
    pp[t] = d0;
    pp[SEQ + t] = d1;
    pp[2 * SEQ + t] = d2;
}

// ---- K3: column-sum part[1024][PSTR] -> accN[600]; 150 blocks x 4 cols ----
__global__ __launch_bounds__(256) void k_reduce(const float* __restrict__ part,
                                                float* __restrict__ accN) {
    __shared__ float sP[4][4];
    const int t = threadIdx.x, lane = t & 63, w = t >> 6;
    const int c4 = blockIdx.x * 4;
    float4 v0 = *(const float4*)&part[(size_t)(t + 256 * 0) * PSTR + c4];
    float4 v1 = *(const float4*)&part[(size_t)(t + 256 * 1) * PSTR + c4];
    float4 v2 = *(const float4*)&part[(size_t)(t + 256 * 2) * PSTR + c4];
    float4 v3 = *(const float4*)&part[(size_t)(t + 256 * 3) * PSTR + c4];
    float sx = v0.x + v1.x + v2.x + v3.x;
    float sy = v0.y + v1.y + v2.y + v3.y;
    float sz = v0.z + v1.z + v2.z + v3.z;
    float sw = v0.w + v1.w + v2.w + v3.w;
#pragma unroll
    for (int off = 1; off < 64; off <<= 1) {
        sx += __shfl_xor(sx, off, 64);
        sy += __shfl_xor(sy, off, 64);
        sz += __shfl_xor(sz, off, 64);
        sw += __shfl_xor(sw, off, 64);
    }
    if (lane == 0) { sP[w][0] = sx; sP[w][1] = sy; sP[w][2] = sz; sP[w][3] = sw; }
    __syncthreads();
    if (t < 4)
        accN[c4 + t] = sP[0][t] + sP[1][t] + sP[2][t] + sP[3][t];
}

extern "C" void kernel_launch(void* const* d_in, const int* in_sizes, int n_in,
                              void* d_out, int out_size, void* d_ws, size_t ws_size,
                              hipStream_t stream) {
    const float* low_capsule = (const float*)d_in[0];   // [1024][200][128]
    const float* B_matrix    = (const float*)d_in[1];   // [1][3][200]
    const float* S_matrix    = (const float*)d_in[2];   // [128][128]
    const int*   seq_len     = (const int*)d_in[3];     // [1024]
    float* out = (float*)d_out;                         // [1024][3][128]

    float* ST   = (float*)d_ws;          // 16384
    float* vL   = ST + 16384;            // 600  (+pad)
    float* Mn   = vL + 640;              // 603  (+pad)
    float* iEn  = Mn + 640;              // 603  (+pad)
    float* acc0 = iEn + 640;             // 600  (+pad)
    float* acc1 = acc0 + 640;            // 600  (+pad)
    float* pw   = acc1 + 640;            // 1024*2*384 = 786432
    float* hsg  = pw + 786432;           // 1024*384   = 393216
    float* part = hsg + 393216;          // 1024*PSTR  = 622592

    k_transpose<<<64, 256, 0, stream>>>(S_matrix, ST);

    // iter 0
    k_scan<<<3, 256, 0, stream>>>(B_matrix, acc0, acc1, vL, Mn, iEn, 0);
    k_wa<<<2 * BATCH, 256, 0, stream>>>(low_capsule, vL, Mn, iEn, seq_len, pw);
    k_mid<<<BATCH, 256, 0, stream>>>(pw, S_matrix, ST, hsg, out, 0);
    k_pc<<<BATCH, 256, 0, stream>>>(low_capsule, hsg, part);
    k_reduce<<<150, 256, 0, stream>>>(part, acc0);

    // iter 1
    k_scan<<<3, 256, 0, stream>>>(B_matrix, acc0, acc1, vL, Mn, iEn, 1);
    k_wa<<<2 * BATCH, 256, 0, stream>>>(low_capsule, vL, Mn, iEn, seq_len, pw);
    k_mid<<<BATCH, 256, 0, stream>>>(pw, S_matrix, ST, hsg, out, 1);
    k_pc<<<BATCH, 256, 0, stream>>>(low_capsule, hsg, part);
    k_reduce<<<150, 256, 0, stream>>>(part, acc1);

    // iter 2 (no Pass C / reduce)
    k_scan<<<3, 256, 0, stream>>>(B_matrix, acc0, acc1, vL, Mn, iEn, 2);
    k_wa<<<2 * BATCH, 256, 0, stream>>>(low_capsule, vL, Mn, iEn, seq_len, pw);
    k_mid<<<BATCH, 256, 0, stream>>>(pw, S_matrix, ST, hsg, out, 2);
}

// Round 10
// 374.378 us; speedup vs baseline: 1.4968x; 1.4968x over previous
//
#include <hip/hip_runtime.h>
#include <math.h>

#define BATCH 1024
#define SEQ   200
#define DIN   128
#define DOUT  128
#define PSTR  608    // partial-delta row stride (floats): 600 data + 8 pad

// ---- K0: transpose S (64 KB, one-time) so both S and S^T are coalesced ----
__global__ __launch_bounds__(256) void k_transpose(const float* __restrict__ S,
                                                   float* __restrict__ ST) {
    int idx = blockIdx.x * 256 + threadIdx.x;   // 0..16383
    int d = idx >> 7, e = idx & 127;
    ST[e * DIN + d] = S[d * DOUT + e];
}

// ---- K_scan: softmax prefix tables. Logits v[k,l] identical for all b;
//      only mask length n differs. Per k: prefix max M[n], inv-denom iE[n].
//      W[b,k,l] = exp(v[l]-M[n_b])*iE[n_b] (l<n_b) == reference softmax. ----
__global__ __launch_bounds__(256) void k_scan(const float* __restrict__ Bm,
                                              const float* __restrict__ a0,
                                              const float* __restrict__ a1,
                                              float* __restrict__ v,
                                              float* __restrict__ Mn,
                                              float* __restrict__ iEn, int iter) {
    __shared__ float sv[SEQ];
    const int k = blockIdx.x, t = threadIdx.x;
    if (t < SEQ) {
        float x = Bm[k * SEQ + t];
        if (iter >= 1) x += a0[k * SEQ + t];
        if (iter >= 2) x += a1[k * SEQ + t];
        sv[t] = x;
        v[k * SEQ + t] = x;
    }
    __syncthreads();
    if (t < SEQ) {
        const int n = t + 1;           // thread computes prefix of length n
        float m = -INFINITY, s = 0.f;
        for (int l = 0; l < n; ++l) {  // LDS broadcast reads (lockstep l)
            float x = sv[l];
            float nm = fmaxf(m, x);
            s = s * expf(m - nm) + expf(x - nm);   // m=-inf: expf(-inf)=0, safe
            m = nm;
        }
        Mn[k * 201 + n] = m;
        iEn[k * 201 + n] = 1.f / s;
    }
}

// ---- K_wa: WA partials = W @ A. Round-10 fixes vs r9:
//      (a) weights computed ONCE per row into LDS (t<100: 3 expf), not
//          64x-redundantly per lane in the stream loop (r9: 39M expf);
//      (b) launch_bounds (256,2) -- (256,4) made the allocator chase
//          8 waves/EU @64 VGPR and spill 148MB (r9 WRITE counter).
//      Stream loop = round-7 PassB (proven no-spill at (256,2)). ----
__global__ __launch_bounds__(256, 2) void k_wa(const float* __restrict__ A,
                                               const float* __restrict__ v,
                                               const float* __restrict__ Mn,
                                               const float* __restrict__ iEn,
                                               const int* __restrict__ seq,
                                               float* __restrict__ pw) {
    __shared__ float4 sW4[100];        // weights for this half's rows (1.6 KB)
    __shared__ float pB[4][3][DIN];    // per-wave partials (6 KB)
    const int t = threadIdx.x, lane = t & 63, w = t >> 6;
    const int b = blockIdx.x >> 1, half = blockIdx.x & 1;
    const int n = seq[b];

    // (0) per-row weights -> LDS (one thread per row, no lane redundancy)
    if (t < 100) {
        const int l = half * 100 + t;
        float w0 = 0.f, w1 = 0.f, w2 = 0.f;
        if (l < n) {
            w0 = expf(v[l]       - Mn[n])       * iEn[n];
            w1 = expf(v[200 + l] - Mn[201 + n]) * iEn[201 + n];
            w2 = expf(v[400 + l] - Mn[402 + n]) * iEn[402 + n];
        }
        sW4[t] = make_float4(w0, w1, w2, 0.f);
    }
    __syncthreads();

    // (1) stream 25 rows/wave, 8-deep named batches, coalesced float2
    const float2* a2 = (const float2*)(A + (size_t)b * (SEQ * DIN));
    const int i0 = w * 25;                    // row index within half
    const int l0 = half * 100 + i0;           // global row
    float h00 = 0.f, h01 = 0.f, h10 = 0.f, h11 = 0.f, h20 = 0.f, h21 = 0.f;

#define WA_FMA(WV, V) \
    h00 = fmaf((WV).x, (V).x, h00); h01 = fmaf((WV).x, (V).y, h01); \
    h10 = fmaf((WV).y, (V).x, h10); h11 = fmaf((WV).y, (V).y, h11); \
    h20 = fmaf((WV).z, (V).x, h20); h21 = fmaf((WV).z, (V).y, h21);

    for (int g = 0; g < 3; ++g) {             // 3 batches of 8 rows
        const int jb = g * 8;
        float2 v0 = a2[(size_t)(l0 + jb + 0) * 64 + lane];
        float2 v1 = a2[(size_t)(l0 + jb + 1) * 64 + lane];
        float2 v2 = a2[(size_t)(l0 + jb + 2) * 64 + lane];
        float2 v3 = a2[(size_t)(l0 + jb + 3) * 64 + lane];
        float2 v4 = a2[(size_t)(l0 + jb + 4) * 64 + lane];
        float2 v5 = a2[(size_t)(l0 + jb + 5) * 64 + lane];
        float2 v6 = a2[(size_t)(l0 + jb + 6) * 64 + lane];
        float2 v7 = a2[(size_t)(l0 + jb + 7) * 64 + lane];
        float4 w0 = sW4[i0 + jb + 0];
        float4 w1 = sW4[i0 + jb + 1];
        float4 w2 = sW4[i0 + jb + 2];
        float4 w3 = sW4[i0 + jb + 3];
        float4 w4 = sW4[i0 + jb + 4];
        float4 w5 = sW4[i0 + jb + 5];
        float4 w6 = sW4[i0 + jb + 6];
        float4 w7 = sW4[i0 + jb + 7];
        WA_FMA(w0, v0) WA_FMA(w1, v1) WA_FMA(w2, v2) WA_FMA(w3, v3)
        WA_FMA(w4, v4) WA_FMA(w5, v5) WA_FMA(w6, v6) WA_FMA(w7, v7)
    }
    {   // remainder row 24
        float2 v0 = a2[(size_t)(l0 + 24) * 64 + lane];
        float4 w0 = sW4[i0 + 24];
        WA_FMA(w0, v0)
    }
#undef WA_FMA

    pB[w][0][2 * lane] = h00; pB[w][0][2 * lane + 1] = h01;
    pB[w][1][2 * lane] = h10; pB[w][1][2 * lane + 1] = h11;
    pB[w][2][2 * lane] = h20; pB[w][2][2 * lane + 1] = h21;
    __syncthreads();
    if (t < DIN) {
        float* dst = pw + ((size_t)b * 2 + half) * 384;
        dst[t]       = pB[0][0][t] + pB[1][0][t] + pB[2][0][t] + pB[3][0][t];
        dst[128 + t] = pB[0][1][t] + pB[1][1][t] + pB[2][1][t] + pB[3][1][t];
        dst[256 + t] = pB[0][2][t] + pB[1][2][t] + pB[2][2][t] + pB[3][2][t];
    }
}

// ---- K_mid: WA -> high -> hS. All-L2 kernel, 1024 blocks. ----
__global__ __launch_bounds__(256) void k_mid(const float* __restrict__ pw,
                                             const float* __restrict__ S,
                                             const float* __restrict__ ST,
                                             float* __restrict__ hs,
                                             float* __restrict__ out, int iter) {
    __shared__ float sWA[3][DIN];
    __shared__ float pb2[2][3][DIN];
    __shared__ float sH[3][DIN];
    const int t = threadIdx.x, b = blockIdx.x;
    const float* p0 = pw + (size_t)b * 2 * 384;
    if (t < DIN) {
        sWA[0][t] = p0[t]       + p0[384 + t];
        sWA[1][t] = p0[128 + t] + p0[384 + 128 + t];
        sWA[2][t] = p0[256 + t] + p0[384 + 256 + t];
    }
    __syncthreads();

    // high_raw = WA @ S : e = t&127, hh = d-half; 8x8 named batches (L2-hot)
    {
        const int e = t & 127, hh = t >> 7;
        const float* Scol = S + e;
        float g0 = 0.f, g1 = 0.f, g2 = 0.f;
        for (int g = 0; g < 8; ++g) {
            const int db = hh * 64 + g * 8;
            float s0 = Scol[(db + 0) * DOUT];
            float s1 = Scol[(db + 1) * DOUT];
            float s2 = Scol[(db + 2) * DOUT];
            float s3 = Scol[(db + 3) * DOUT];
            float s4 = Scol[(db + 4) * DOUT];
            float s5 = Scol[(db + 5) * DOUT];
            float s6 = Scol[(db + 6) * DOUT];
            float s7 = Scol[(db + 7) * DOUT];
#define HB_FMA(J, SV) \
            g0 = fmaf(sWA[0][db + J], SV, g0); \
            g1 = fmaf(sWA[1][db + J], SV, g1); \
            g2 = fmaf(sWA[2][db + J], SV, g2);
            HB_FMA(0, s0) HB_FMA(1, s1) HB_FMA(2, s2) HB_FMA(3, s3)
            HB_FMA(4, s4) HB_FMA(5, s5) HB_FMA(6, s6) HB_FMA(7, s7)
#undef HB_FMA
        }
        pb2[hh][0][e] = g0; pb2[hh][1][e] = g1; pb2[hh][2][e] = g2;
    }
    __syncthreads();

    // combine halves + squash; write out on last iter
    if (t < DIN) {
        float g0 = pb2[0][0][t] + pb2[1][0][t];
        float g1 = pb2[0][1][t] + pb2[1][1][t];
        float g2 = pb2[0][2][t] + pb2[1][2][t];
        float sq = g0 * g0 + g1 * g1 + g2 * g2;
        float scale = sq / (1.f + sq) / sqrtf(sq + 1e-9f);
        g0 *= scale; g1 *= scale; g2 *= scale;
        if (iter == 2) {
            size_t o = (size_t)b * 3 * DOUT + t;
            out[o] = g0; out[o + DOUT] = g1; out[o + 2 * DOUT] = g2;
        } else {
            sH[0][t] = g0; sH[1][t] = g1; sH[2][t] = g2;
        }
    }
    if (iter == 2) return;   // uniform exit
    __syncthreads();

    // hS = high @ S^T : d = t&127, hh = e-half; 8x8 named batches
    {
        const int d = t & 127, hh = t >> 7;
        const float* STcol = ST + d;
        float s0a = 0.f, s1a = 0.f, s2a = 0.f;
        for (int g = 0; g < 8; ++g) {
            const int eb = hh * 64 + g * 8;
            float s0 = STcol[(eb + 0) * DIN];
            float s1 = STcol[(eb + 1) * DIN];
            float s2 = STcol[(eb + 2) * DIN];
            float s3 = STcol[(eb + 3) * DIN];
            float s4 = STcol[(eb + 4) * DIN];
            float s5 = STcol[(eb + 5) * DIN];
            float s6 = STcol[(eb + 6) * DIN];
            float s7 = STcol[(eb + 7) * DIN];
#define HS_FMA(J, SV) \
            s0a = fmaf(sH[0][eb + J], SV, s0a); \
            s1a = fmaf(sH[1][eb + J], SV, s1a); \
            s2a = fmaf(sH[2][eb + J], SV, s2a);
            HS_FMA(0, s0) HS_FMA(1, s1) HS_FMA(2, s2) HS_FMA(3, s3)
            HS_FMA(4, s4) HS_FMA(5, s5) HS_FMA(6, s6) HS_FMA(7, s7)
#undef HS_FMA
        }
        pb2[hh][0][d] = s0a; pb2[hh][1][d] = s1a; pb2[hh][2][d] = s2a;
    }
    __syncthreads();
    if (t < DIN) {
        float* dst = hs + (size_t)b * 384;
        dst[t]       = pb2[0][0][t] + pb2[1][0][t];
        dst[128 + t] = pb2[0][1][t] + pb2[1][1][t];
        dst[256 + t] = pb2[0][2][t] + pb2[1][2][t];
    }
}

// ---- K_pc: B_delta partials = hS @ A^T. Round-10 rewrite: COALESCED.
//      Lane = dim-pair (float2), one wave-load = full 512B row (4 lines,
//      vs the r4-r9 per-thread-row gather = 64 lines/inst). Lane-local
//      3 dots, shfl_xor butterfly per row, LDS collect, coalesced store. ----
__global__ __launch_bounds__(256, 2) void k_pc(const float* __restrict__ A,
                                               const float* __restrict__ hs,
                                               float* __restrict__ part) {
    __shared__ float sD0[SEQ], sD1[SEQ], sD2[SEQ];
    const int t = threadIdx.x, lane = t & 63, w = t >> 6;
    const int b = blockIdx.x;
    const float2* h2 = (const float2*)(hs + (size_t)b * 384);
    const float2 ha = h2[lane];           // hS[0], dims 2lane..2lane+1
    const float2 hb = h2[64 + lane];      // hS[1]
    const float2 hc = h2[128 + lane];     // hS[2]
    const float2* a2 = (const float2*)(A + (size_t)b * (SEQ * DIN));
    const int l0 = w * 50;

#define PC_ROW(V, L) { \
    float p0 = (V).x * ha.x + (V).y * ha.y; \
    float p1 = (V).x * hb.x + (V).y * hb.y; \
    float p2 = (V).x * hc.x + (V).y * hc.y; \
    _Pragma("unroll") \
    for (int off = 1; off < 64; off <<= 1) { \
        p0 += __shfl_xor(p0, off, 64); \
        p1 += __shfl_xor(p1, off, 64); \
        p2 += __shfl_xor(p2, off, 64); } \
    if (lane == 0) { sD0[L] = p0; sD1[L] = p1; sD2[L] = p2; } }

    for (int g = 0; g < 6; ++g) {          // 6 batches of 8 rows
        const int lb = l0 + g * 8;
        float2 v0 = a2[(size_t)(lb + 0) * 64 + lane];
        float2 v1 = a2[(size_t)(lb + 1) * 64 + lane];
        float2 v2 = a2[(size_t)(lb + 2) * 64 + lane];
        float2 v3 = a2[(size_t)(lb + 3) * 64 + lane];
        float2 v4 = a2[(size_t)(lb + 4) * 64 + lane];
        float2 v5 = a2[(size_t)(lb + 5) * 64 + lane];
        float2 v6 = a2[(size_t)(lb + 6) * 64 + lane];
        float2 v7 = a2[(size_t)(lb + 7) * 64 + lane];
        PC_ROW(v0, lb + 0) PC_ROW(v1, lb + 1) PC_ROW(v2, lb + 2) PC_ROW(v3, lb + 3)
        PC_ROW(v4, lb + 4) PC_ROW(v5, lb + 5) PC_ROW(v6, lb + 6) PC_ROW(v7, lb + 7)
    }
    {   // remainder rows l0+48, l0+49
        const int lb = l0 + 48;
        float2 v0 = a2[(size_t)(lb + 0) * 64 + lane];
        float2 v1 = a2[(size_t)(lb + 1) * 64 + lane];
        PC_ROW(v0, lb + 0) PC_ROW(v1, lb + 1)
    }
#undef PC_ROW

    __syncthreads();
    if (t < SEQ) {
        float* pp = part + (size_t)b * PSTR;
        pp[t] = sD0[t];
        pp[SEQ + t] = sD1[t];
        pp[2 * SEQ + t] = sD2[t];
    }
}

// ---- K3: column-sum part[1024][PSTR] -> accN[600]; 150 blocks x 4 cols ----
__global__ __launch_bounds__(256) void k_reduce(const float* __restrict__ part,
                                                float* __restrict__ accN) {
    __shared__ float sP[4][4];
    const int t = threadIdx.x, lane = t & 63, w = t >> 6;
    const int c4 = blockIdx.x * 4;
    float4 v0 = *(const float4*)&part[(size_t)(t + 256 * 0) * PSTR + c4];
    float4 v1 = *(const float4*)&part[(size_t)(t + 256 * 1) * PSTR + c4];
    float4 v2 = *(const float4*)&part[(size_t)(t + 256 * 2) * PSTR + c4];
    float4 v3 = *(const float4*)&part[(size_t)(t + 256 * 3) * PSTR + c4];
    float sx = v0.x + v1.x + v2.x + v3.x;
    float sy = v0.y + v1.y + v2.y + v3.y;
    float sz = v0.z + v1.z + v2.z + v3.z;
    float sw = v0.w + v1.w + v2.w + v3.w;
#pragma unroll
    for (int off = 1; off < 64; off <<= 1) {
        sx += __shfl_xor(sx, off, 64);
        sy += __shfl_xor(sy, off, 64);
        sz += __shfl_xor(sz, off, 64);
        sw += __shfl_xor(sw, off, 64);
    }
    if (lane == 0) { sP[w][0] = sx; sP[w][1] = sy; sP[w][2] = sz; sP[w][3] = sw; }
    __syncthreads();
    if (t < 4)
        accN[c4 + t] = sP[0][t] + sP[1][t] + sP[2][t] + sP[3][t];
}

extern "C" void kernel_launch(void* const* d_in, const int* in_sizes, int n_in,
                              void* d_out, int out_size, void* d_ws, size_t ws_size,
                              hipStream_t stream) {
    const float* low_capsule = (const float*)d_in[0];   // [1024][200][128]
    const float* B_matrix    = (const float*)d_in[1];   // [1][3][200]
    const float* S_matrix    = (const float*)d_in[2];   // [128][128]
    const int*   seq_len     = (const int*)d_in[3];     // [1024]
    float* out = (float*)d_out;                         // [1024][3][128]

    float* ST   = (float*)d_ws;          // 16384
    float* vL   = ST + 16384;            // 600  (+pad)
    float* Mn   = vL + 640;              // 603  (+pad)
    float* iEn  = Mn + 640;              // 603  (+pad)
    float* acc0 = iEn + 640;             // 600  (+pad)
    float* acc1 = acc0 + 640;            // 600  (+pad)
    float* pw   = acc1 + 640;            // 1024*2*384 = 786432
    float* hsg  = pw + 786432;           // 1024*384   = 393216
    float* part = hsg + 393216;          // 1024*PSTR  = 622592

    k_transpose<<<64, 256, 0, stream>>>(S_matrix, ST);

    // iter 0
    k_scan<<<3, 256, 0, stream>>>(B_matrix, acc0, acc1, vL, Mn, iEn, 0);
    k_wa<<<2 * BATCH, 256, 0, stream>>>(low_capsule, vL, Mn, iEn, seq_len, pw);
    k_mid<<<BATCH, 256, 0, stream>>>(pw, S_matrix, ST, hsg, out, 0);
    k_pc<<<BATCH, 256, 0, stream>>>(low_capsule, hsg, part);
    k_reduce<<<150, 256, 0, stream>>>(part, acc0);

    // iter 1
    k_scan<<<3, 256, 0, stream>>>(B_matrix, acc0, acc1, vL, Mn, iEn, 1);
    k_wa<<<2 * BATCH, 256, 0, stream>>>(low_capsule, vL, Mn, iEn, seq_len, pw);
    k_mid<<<BATCH, 256, 0, stream>>>(pw, S_matrix, ST, hsg, out, 1);
    k_pc<<<BATCH, 256, 0, stream>>>(low_capsule, hsg, part);
    k_reduce<<<150, 256, 0, stream>>>(part, acc1);

    // iter 2 (no Pass C / reduce)
    k_scan<<<3, 256, 0, stream>>>(B_matrix, acc0, acc1, vL, Mn, iEn, 2);
    k_wa<<<2 * BATCH, 256, 0, stream>>>(low_capsule, vL, Mn, iEn, seq_len, pw);
    k_mid<<<BATCH, 256, 0, stream>>>(pw, S_matrix, ST, hsg, out, 2);
}

// Round 11
// 337.269 us; speedup vs baseline: 1.6615x; 1.1100x over previous
//
#include <hip/hip_runtime.h>
#include <math.h>

#define BATCH 1024
#define SEQ   200
#define DIN   128
#define DOUT  128

// ---- K0: transpose S (one-time) + zero the atomic accumulators ----
__global__ __launch_bounds__(256) void k_transpose(const float* __restrict__ S,
                                                   float* __restrict__ ST,
                                                   float* __restrict__ acc0,
                                                   float* __restrict__ acc1) {
    int idx = blockIdx.x * 256 + threadIdx.x;   // 0..16383
    int d = idx >> 7, e = idx & 127;
    ST[e * DIN + d] = S[d * DOUT + e];
    if (idx < 600) { acc0[idx] = 0.f; acc1[idx] = 0.f; }   // re-zero every replay
}

// ---- K_scan: softmax prefix tables. Logits v[k,l] identical for all b;
//      only mask length n differs. Per k: prefix max M[n], inv-denom iE[n].
//      W[b,k,l] = exp(v[l]-M[n_b])*iE[n_b] (l<n_b) == reference softmax. ----
__global__ __launch_bounds__(256) void k_scan(const float* __restrict__ Bm,
                                              const float* __restrict__ a0,
                                              const float* __restrict__ a1,
                                              float* __restrict__ v,
                                              float* __restrict__ Mn,
                                              float* __restrict__ iEn, int iter) {
    __shared__ float sv[SEQ];
    const int k = blockIdx.x, t = threadIdx.x;
    if (t < SEQ) {
        float x = Bm[k * SEQ + t];
        if (iter >= 1) x += a0[k * SEQ + t];
        if (iter >= 2) x += a1[k * SEQ + t];
        sv[t] = x;
        v[k * SEQ + t] = x;
    }
    __syncthreads();
    if (t < SEQ) {
        const int n = t + 1;           // thread computes prefix of length n
        float m = -INFINITY, s = 0.f;
        for (int l = 0; l < n; ++l) {  // LDS broadcast reads (lockstep l)
            float x = sv[l];
            float nm = fmaxf(m, x);
            s = s * expf(m - nm) + expf(x - nm);   // m=-inf: expf(-inf)=0, safe
            m = nm;
        }
        Mn[k * 201 + n] = m;
        iEn[k * 201 + n] = 1.f / s;
    }
}

// ---- K_fused: one routing iteration for one batch b per block.
//      weights(table) -> WA = W@A (float4 stream) -> high = squash(WA@S)
//      -> hS = high@S^T -> B_delta partials = hS@A^T (float4 stream)
//      -> atomicAdd into accN (replaces part[] + k_reduce).
//      Thread map for A streams: rg = t>>5 (8 row streams), q = t&31
//      (dim quad) -> one wave-inst = two full 512B rows, 16B/lane
//      (the 6.3TB/s ubench pattern; r10's float2 streams sat at 2TB/s).
//      (256,2): allocator settles ~80-100 VGPR, no spill (r7/r10 precedent).
__global__ __launch_bounds__(256, 2) void k_fused(
    const float* __restrict__ A,         // [B][200][128]
    const float* __restrict__ v,         // [3][200] logits
    const float* __restrict__ Mn,        // [3][201] prefix max
    const float* __restrict__ iEn,       // [3][201] prefix inv-denom
    const int* __restrict__ seq,         // [B]
    const float* __restrict__ S,         // [128][128]
    const float* __restrict__ ST,        // [128][128]
    float* __restrict__ accN,            // [600] atomic B_delta accumulator
    float* __restrict__ out, int iter) {
    __shared__ float4 sW4[SEQ];          // per-row weights (3.2 KB)
    __shared__ float4 pBq[8][3][32];     // WA partials (12 KB)
    __shared__ float sWA[3][DIN];        // 1.5 KB
    __shared__ float pb2[2][3][DIN];     // 3 KB
    __shared__ float sH[3][DIN];         // 1.5 KB
    __shared__ float sHS[3][DIN];        // 1.5 KB
    __shared__ float sD0[SEQ], sD1[SEQ], sD2[SEQ];   // 2.4 KB

    const int t = threadIdx.x, b = blockIdx.x;
    const int n = seq[b];

    // (0) per-row weights from the prefix tables (3 expf per row, once)
    if (t < SEQ) {
        float w0 = 0.f, w1 = 0.f, w2 = 0.f;
        if (t < n) {
            w0 = expf(v[t]       - Mn[n])       * iEn[n];
            w1 = expf(v[200 + t] - Mn[201 + n]) * iEn[201 + n];
            w2 = expf(v[400 + t] - Mn[402 + n]) * iEn[402 + n];
        }
        sW4[t] = make_float4(w0, w1, w2, 0.f);
    }
    __syncthreads();

    const int q = t & 31;          // dim quad: dims 4q..4q+3
    const int rg = t >> 5;         // row stream 0..7: rows rg+8s
    const float4* a4 = (const float4*)(A + (size_t)b * (SEQ * DIN)); // row stride 32

    // (1) WA stream: 25 rows/thread, 8-deep named float4 batches
    float4 hA = make_float4(0.f, 0.f, 0.f, 0.f);
    float4 hB = hA, hC = hA;

#define WA_ROW(U, W) \
    hA.x = fmaf((W).x, (U).x, hA.x); hA.y = fmaf((W).x, (U).y, hA.y); \
    hA.z = fmaf((W).x, (U).z, hA.z); hA.w = fmaf((W).x, (U).w, hA.w); \
    hB.x = fmaf((W).y, (U).x, hB.x); hB.y = fmaf((W).y, (U).y, hB.y); \
    hB.z = fmaf((W).y, (U).z, hB.z); hB.w = fmaf((W).y, (U).w, hB.w); \
    hC.x = fmaf((W).z, (U).x, hC.x); hC.y = fmaf((W).z, (U).y, hC.y); \
    hC.z = fmaf((W).z, (U).z, hC.z); hC.w = fmaf((W).z, (U).w, hC.w);

    for (int g = 0; g < 3; ++g) {              // rows rg+64g+8j, j=0..7
        const int r0 = rg + g * 64;
        float4 u0 = a4[(size_t)(r0 +  0) * 32 + q];
        float4 u1 = a4[(size_t)(r0 +  8) * 32 + q];
        float4 u2 = a4[(size_t)(r0 + 16) * 32 + q];
        float4 u3 = a4[(size_t)(r0 + 24) * 32 + q];
        float4 u4 = a4[(size_t)(r0 + 32) * 32 + q];
        float4 u5 = a4[(size_t)(r0 + 40) * 32 + q];
        float4 u6 = a4[(size_t)(r0 + 48) * 32 + q];
        float4 u7 = a4[(size_t)(r0 + 56) * 32 + q];
        float4 w0 = sW4[r0], w1 = sW4[r0 + 8], w2 = sW4[r0 + 16], w3 = sW4[r0 + 24];
        float4 w4 = sW4[r0 + 32], w5 = sW4[r0 + 40], w6 = sW4[r0 + 48], w7 = sW4[r0 + 56];
        WA_ROW(u0, w0) WA_ROW(u1, w1) WA_ROW(u2, w2) WA_ROW(u3, w3)
        WA_ROW(u4, w4) WA_ROW(u5, w5) WA_ROW(u6, w6) WA_ROW(u7, w7)
    }
    {   // remainder row rg+192
        float4 u0 = a4[(size_t)(rg + 192) * 32 + q];
        float4 w0 = sW4[rg + 192];
        WA_ROW(u0, w0)
    }
#undef WA_ROW

    pBq[rg][0][q] = hA; pBq[rg][1][q] = hB; pBq[rg][2][q] = hC;
    __syncthreads();

    // (2) reduce the 8 row-streams -> sWA[3][128]
    if (t < 96) {
        const int k = t >> 5, qq = t & 31;
        float4 a0 = pBq[0][k][qq], a1 = pBq[1][k][qq];
        float4 a2 = pBq[2][k][qq], a3 = pBq[3][k][qq];
        float4 a4v = pBq[4][k][qq], a5 = pBq[5][k][qq];
        float4 a6 = pBq[6][k][qq], a7 = pBq[7][k][qq];
        float4 r;
        r.x = ((a0.x + a1.x) + (a2.x + a3.x)) + ((a4v.x + a5.x) + (a6.x + a7.x));
        r.y = ((a0.y + a1.y) + (a2.y + a3.y)) + ((a4v.y + a5.y) + (a6.y + a7.y));
        r.z = ((a0.z + a1.z) + (a2.z + a3.z)) + ((a4v.z + a5.z) + (a6.z + a7.z));
        r.w = ((a0.w + a1.w) + (a2.w + a3.w)) + ((a4v.w + a5.w) + (a6.w + a7.w));
        *(float4*)&sWA[k][4 * qq] = r;
    }
    __syncthreads();

    // (3) high_raw = WA @ S : e = t&127, hh = d-half; coalesced, L2-hot
    {
        const int e = t & 127, hh = t >> 7;
        const float* Scol = S + e;
        float g0 = 0.f, g1 = 0.f, g2 = 0.f;
        for (int g = 0; g < 8; ++g) {
            const int db = hh * 64 + g * 8;
            float s0 = Scol[(db + 0) * DOUT];
            float s1 = Scol[(db + 1) * DOUT];
            float s2 = Scol[(db + 2) * DOUT];
            float s3 = Scol[(db + 3) * DOUT];
            float s4 = Scol[(db + 4) * DOUT];
            float s5 = Scol[(db + 5) * DOUT];
            float s6 = Scol[(db + 6) * DOUT];
            float s7 = Scol[(db + 7) * DOUT];
#define HB_FMA(J, SV) \
            g0 = fmaf(sWA[0][db + J], SV, g0); \
            g1 = fmaf(sWA[1][db + J], SV, g1); \
            g2 = fmaf(sWA[2][db + J], SV, g2);
            HB_FMA(0, s0) HB_FMA(1, s1) HB_FMA(2, s2) HB_FMA(3, s3)
            HB_FMA(4, s4) HB_FMA(5, s5) HB_FMA(6, s6) HB_FMA(7, s7)
#undef HB_FMA
        }
        pb2[hh][0][e] = g0; pb2[hh][1][e] = g1; pb2[hh][2][e] = g2;
    }
    __syncthreads();

    // (3c) combine + squash; last iter writes out and exits (uniform)
    if (t < DIN) {
        float g0 = pb2[0][0][t] + pb2[1][0][t];
        float g1 = pb2[0][1][t] + pb2[1][1][t];
        float g2 = pb2[0][2][t] + pb2[1][2][t];
        float sq = g0 * g0 + g1 * g1 + g2 * g2;
        float scale = sq / (1.f + sq) / sqrtf(sq + 1e-9f);
        g0 *= scale; g1 *= scale; g2 *= scale;
        if (iter == 2) {
            size_t o = (size_t)b * 3 * DOUT + t;
            out[o] = g0; out[o + DOUT] = g1; out[o + 2 * DOUT] = g2;
        } else {
            sH[0][t] = g0; sH[1][t] = g1; sH[2][t] = g2;
        }
    }
    if (iter == 2) return;
    __syncthreads();

    // (4) hS = high @ S^T : d = t&127, hh = e-half
    {
        const int d = t & 127, hh = t >> 7;
        const float* STcol = ST + d;
        float s0a = 0.f, s1a = 0.f, s2a = 0.f;
        for (int g = 0; g < 8; ++g) {
            const int eb = hh * 64 + g * 8;
            float s0 = STcol[(eb + 0) * DIN];
            float s1 = STcol[(eb + 1) * DIN];
            float s2 = STcol[(eb + 2) * DIN];
            float s3 = STcol[(eb + 3) * DIN];
            float s4 = STcol[(eb + 4) * DIN];
            float s5 = STcol[(eb + 5) * DIN];
            float s6 = STcol[(eb + 6) * DIN];
            float s7 = STcol[(eb + 7) * DIN];
#define HS_FMA(J, SV) \
            s0a = fmaf(sH[0][eb + J], SV, s0a); \
            s1a = fmaf(sH[1][eb + J], SV, s1a); \
            s2a = fmaf(sH[2][eb + J], SV, s2a);
            HS_FMA(0, s0) HS_FMA(1, s1) HS_FMA(2, s2) HS_FMA(3, s3)
            HS_FMA(4, s4) HS_FMA(5, s5) HS_FMA(6, s6) HS_FMA(7, s7)
#undef HS_FMA
        }
        pb2[hh][0][d] = s0a; pb2[hh][1][d] = s1a; pb2[hh][2][d] = s2a;
    }
    __syncthreads();
    if (t < DIN) {
        sHS[0][t] = pb2[0][0][t] + pb2[1][0][t];
        sHS[1][t] = pb2[0][1][t] + pb2[1][1][t];
        sHS[2][t] = pb2[0][2][t] + pb2[1][2][t];
    }
    __syncthreads();

    // (5) PC stream: B_delta[l] = hS . A[l]. Same float4 map; per-row dot
    //     reduced across the 32 quads with a 5-step half-wave butterfly.
    {
        const float4 x0 = *(const float4*)&sHS[0][4 * q];
        const float4 x1 = *(const float4*)&sHS[1][4 * q];
        const float4 x2 = *(const float4*)&sHS[2][4 * q];

#define PC_ROW(U, R) { \
        float p0 = (U).x * x0.x + (U).y * x0.y + (U).z * x0.z + (U).w * x0.w; \
        float p1 = (U).x * x1.x + (U).y * x1.y + (U).z * x1.z + (U).w * x1.w; \
        float p2 = (U).x * x2.x + (U).y * x2.y + (U).z * x2.z + (U).w * x2.w; \
        _Pragma("unroll") \
        for (int off = 1; off < 32; off <<= 1) { \
            p0 += __shfl_xor(p0, off, 64); \
            p1 += __shfl_xor(p1, off, 64); \
            p2 += __shfl_xor(p2, off, 64); } \
        if (q == 0) { sD0[R] = p0; sD1[R] = p1; sD2[R] = p2; } }

        for (int g = 0; g < 3; ++g) {
            const int r0 = rg + g * 64;
            float4 u0 = a4[(size_t)(r0 +  0) * 32 + q];
            float4 u1 = a4[(size_t)(r0 +  8) * 32 + q];
            float4 u2 = a4[(size_t)(r0 + 16) * 32 + q];
            float4 u3 = a4[(size_t)(r0 + 24) * 32 + q];
            float4 u4 = a4[(size_t)(r0 + 32) * 32 + q];
            float4 u5 = a4[(size_t)(r0 + 40) * 32 + q];
            float4 u6 = a4[(size_t)(r0 + 48) * 32 + q];
            float4 u7 = a4[(size_t)(r0 + 56) * 32 + q];
            PC_ROW(u0, r0 +  0) PC_ROW(u1, r0 +  8) PC_ROW(u2, r0 + 16) PC_ROW(u3, r0 + 24)
            PC_ROW(u4, r0 + 32) PC_ROW(u5, r0 + 40) PC_ROW(u6, r0 + 48) PC_ROW(u7, r0 + 56)
        }
        {
            float4 u0 = a4[(size_t)(rg + 192) * 32 + q];
            PC_ROW(u0, rg + 192)
        }
#undef PC_ROW
    }
    __syncthreads();

    // (6) global B_delta accumulation (replaces part[] + k_reduce)
    if (t < SEQ) {
        atomicAdd(&accN[t],       sD0[t]);
        atomicAdd(&accN[200 + t], sD1[t]);
        atomicAdd(&accN[400 + t], sD2[t]);
    }
}

extern "C" void kernel_launch(void* const* d_in, const int* in_sizes, int n_in,
                              void* d_out, int out_size, void* d_ws, size_t ws_size,
                              hipStream_t stream) {
    const float* low_capsule = (const float*)d_in[0];   // [1024][200][128]
    const float* B_matrix    = (const float*)d_in[1];   // [1][3][200]
    const float* S_matrix    = (const float*)d_in[2];   // [128][128]
    const int*   seq_len     = (const int*)d_in[3];     // [1024]
    float* out = (float*)d_out;                         // [1024][3][128]

    float* ST   = (float*)d_ws;          // 16384
    float* vL   = ST + 16384;            // 600  (+pad)
    float* Mn   = vL + 640;              // 603  (+pad)
    float* iEn  = Mn + 640;              // 603  (+pad)
    float* acc0 = iEn + 640;             // 600  (+pad)
    float* acc1 = acc0 + 640;            // 600  (+pad)

    k_transpose<<<64, 256, 0, stream>>>(S_matrix, ST, acc0, acc1);

    // iter 0
    k_scan<<<3, 256, 0, stream>>>(B_matrix, acc0, acc1, vL, Mn, iEn, 0);
    k_fused<<<BATCH, 256, 0, stream>>>(low_capsule, vL, Mn, iEn, seq_len,
                                       S_matrix, ST, acc0, out, 0);
    // iter 1
    k_scan<<<3, 256, 0, stream>>>(B_matrix, acc0, acc1, vL, Mn, iEn, 1);
    k_fused<<<BATCH, 256, 0, stream>>>(low_capsule, vL, Mn, iEn, seq_len,
                                       S_matrix, ST, acc1, out, 1);
    // iter 2 (no PC / no accumulation)
    k_scan<<<3, 256, 0, stream>>>(B_matrix, acc0, acc1, vL, Mn, iEn, 2);
    k_fused<<<BATCH, 256, 0, stream>>>(low_capsule, vL, Mn, iEn, seq_len,
                                       S_matrix, ST, acc1, out, 2);
}

// Round 12
// 320.478 us; speedup vs baseline: 1.7486x; 1.0524x over previous
//
#include <hip/hip_runtime.h>
#include <math.h>

#define BATCH 1024
#define SEQ   200
#define DIN   128
#define DOUT  128

// ---- K0: transpose S (one-time) + zero the atomic accumulators ----
__global__ __launch_bounds__(256) void k_transpose(const float* __restrict__ S,
                                                   float* __restrict__ ST,
                                                   float* __restrict__ acc0,
                                                   float* __restrict__ acc1) {
    int idx = blockIdx.x * 256 + threadIdx.x;   // 0..16383
    int d = idx >> 7, e = idx & 127;
    ST[e * DIN + d] = S[d * DOUT + e];
    if (idx < 600) { acc0[idx] = 0.f; acc1[idx] = 0.f; }   // re-zero every replay
}

// ---- K_scan: softmax prefix tables. Logits v[k,l] identical for all b;
//      only mask length n differs. Per k: prefix max M[n], inv-denom iE[n].
//      W[b,k,l] = exp(v[l]-M[n_b])*iE[n_b] (l<n_b) == reference softmax. ----
__global__ __launch_bounds__(256) void k_scan(const float* __restrict__ Bm,
                                              const float* __restrict__ a0,
                                              const float* __restrict__ a1,
                                              float* __restrict__ v,
                                              float* __restrict__ Mn,
                                              float* __restrict__ iEn, int iter) {
    __shared__ float sv[SEQ];
    const int k = blockIdx.x, t = threadIdx.x;
    if (t < SEQ) {
        float x = Bm[k * SEQ + t];
        if (iter >= 1) x += a0[k * SEQ + t];
        if (iter >= 2) x += a1[k * SEQ + t];
        sv[t] = x;
        v[k * SEQ + t] = x;
    }
    __syncthreads();
    if (t < SEQ) {
        const int n = t + 1;           // thread computes prefix of length n
        float m = -INFINITY, s = 0.f;
        for (int l = 0; l < n; ++l) {  // LDS broadcast reads (lockstep l)
            float x = sv[l];
            float nm = fmaxf(m, x);
            s = s * expf(m - nm) + expf(x - nm);   // m=-inf: expf(-inf)=0, safe
            m = nm;
        }
        Mn[k * 201 + n] = m;
        iEn[k * 201 + n] = 1.f / s;
    }
}

// ---- K_fused: one routing iteration for one batch b per block.
//      Round-12: r11's fused structure, but the A-streams reverted to the
//      session's EMPIRICALLY FASTEST maps:
//        WA: r7 PassB -- wave w owns rows 50w..50w+49; lane = dim-pair
//            (float2), one wave-inst = one full 512B row; 10-deep batches.
//            (r11's rg/q float4 map measured 1.3 TB/s vs r7's ~3.5-4.)
//        PC: r7 per-thread-row float4 gather -- A is L2/L3-hot from WA.
//      Weights from k_scan tables; B_delta via atomicAdd (r11, proven).
//      (256,2): allocator settles ~80-100 VGPR, no spill (r7/r11). ----
__global__ __launch_bounds__(256, 2) void k_fused(
    const float* __restrict__ A,         // [B][200][128]
    const float* __restrict__ v,         // [3][200] logits
    const float* __restrict__ Mn,        // [3][201] prefix max
    const float* __restrict__ iEn,       // [3][201] prefix inv-denom
    const int* __restrict__ seq,         // [B]
    const float* __restrict__ S,         // [128][128]
    const float* __restrict__ ST,        // [128][128]
    float* __restrict__ accN,            // [600] atomic B_delta accumulator
    float* __restrict__ out, int iter) {
    __shared__ float4 sW4[SEQ];          // per-row weights (3.2 KB)
    __shared__ float pB[4][3][DIN];      // WA partials (6 KB)
    __shared__ float sWA[3][DIN];        // 1.5 KB
    __shared__ float pb2[2][3][DIN];     // 3 KB
    __shared__ float sH[3][DIN];         // 1.5 KB
    __shared__ float sHS[3][DIN];        // 1.5 KB

    const int t = threadIdx.x;
    const int lane = t & 63, w = t >> 6;
    const int b = blockIdx.x;
    const int n = seq[b];

    // (0) per-row weights from the prefix tables (3 expf per row, once)
    if (t < SEQ) {
        float w0 = 0.f, w1 = 0.f, w2 = 0.f;
        if (t < n) {
            w0 = expf(v[t]       - Mn[n])       * iEn[n];
            w1 = expf(v[200 + t] - Mn[201 + n]) * iEn[201 + n];
            w2 = expf(v[400 + t] - Mn[402 + n]) * iEn[402 + n];
        }
        sW4[t] = make_float4(w0, w1, w2, 0.f);
    }
    __syncthreads();

    // (1) WA stream: wave w sums rows 50w..50w+49; lane = dims 2lane,2lane+1.
    //     10-deep named-scalar float2 batches (5 x 10 rows).
    {
        const float2* a2 = (const float2*)(A + (size_t)b * (SEQ * DIN));
        float h00 = 0.f, h01 = 0.f, h10 = 0.f, h11 = 0.f, h20 = 0.f, h21 = 0.f;
        const int l0 = w * 50;

#define WA_FMA(WV, V) \
        h00 = fmaf((WV).x, (V).x, h00); h01 = fmaf((WV).x, (V).y, h01); \
        h10 = fmaf((WV).y, (V).x, h10); h11 = fmaf((WV).y, (V).y, h11); \
        h20 = fmaf((WV).z, (V).x, h20); h21 = fmaf((WV).z, (V).y, h21);

        for (int g = 0; g < 5; ++g) {
            const int lb = l0 + g * 10;
            float2 v0 = a2[(size_t)(lb + 0) * 64 + lane];
            float2 v1 = a2[(size_t)(lb + 1) * 64 + lane];
            float2 v2 = a2[(size_t)(lb + 2) * 64 + lane];
            float2 v3 = a2[(size_t)(lb + 3) * 64 + lane];
            float2 v4 = a2[(size_t)(lb + 4) * 64 + lane];
            float2 v5 = a2[(size_t)(lb + 5) * 64 + lane];
            float2 v6 = a2[(size_t)(lb + 6) * 64 + lane];
            float2 v7 = a2[(size_t)(lb + 7) * 64 + lane];
            float2 v8 = a2[(size_t)(lb + 8) * 64 + lane];
            float2 v9 = a2[(size_t)(lb + 9) * 64 + lane];
            float4 w0 = sW4[lb + 0];
            float4 w1 = sW4[lb + 1];
            float4 w2 = sW4[lb + 2];
            float4 w3 = sW4[lb + 3];
            float4 w4 = sW4[lb + 4];
            float4 w5 = sW4[lb + 5];
            float4 w6 = sW4[lb + 6];
            float4 w7 = sW4[lb + 7];
            float4 w8 = sW4[lb + 8];
            float4 w9 = sW4[lb + 9];
            WA_FMA(w0, v0) WA_FMA(w1, v1) WA_FMA(w2, v2) WA_FMA(w3, v3)
            WA_FMA(w4, v4) WA_FMA(w5, v5) WA_FMA(w6, v6) WA_FMA(w7, v7)
            WA_FMA(w8, v8) WA_FMA(w9, v9)
        }
#undef WA_FMA
        pB[w][0][2 * lane] = h00; pB[w][0][2 * lane + 1] = h01;
        pB[w][1][2 * lane] = h10; pB[w][1][2 * lane + 1] = h11;
        pB[w][2][2 * lane] = h20; pB[w][2][2 * lane + 1] = h21;
    }
    __syncthreads();

    // (2) reduce WA across waves
    if (t < DIN) {
#pragma unroll
        for (int k = 0; k < 3; ++k)
            sWA[k][t] = pB[0][k][t] + pB[1][k][t] + pB[2][k][t] + pB[3][k][t];
    }
    __syncthreads();

    // (3) high_raw = WA @ S : e = t&127, hh = d-half; 8x8 named batches (L2-hot)
    {
        const int e = t & 127, hh = t >> 7;
        const float* Scol = S + e;
        float g0 = 0.f, g1 = 0.f, g2 = 0.f;
        for (int g = 0; g < 8; ++g) {
            const int db = hh * 64 + g * 8;
            float s0 = Scol[(db + 0) * DOUT];
            float s1 = Scol[(db + 1) * DOUT];
            float s2 = Scol[(db + 2) * DOUT];
            float s3 = Scol[(db + 3) * DOUT];
            float s4 = Scol[(db + 4) * DOUT];
            float s5 = Scol[(db + 5) * DOUT];
            float s6 = Scol[(db + 6) * DOUT];
            float s7 = Scol[(db + 7) * DOUT];
#define HB_FMA(J, SV) \
            g0 = fmaf(sWA[0][db + J], SV, g0); \
            g1 = fmaf(sWA[1][db + J], SV, g1); \
            g2 = fmaf(sWA[2][db + J], SV, g2);
            HB_FMA(0, s0) HB_FMA(1, s1) HB_FMA(2, s2) HB_FMA(3, s3)
            HB_FMA(4, s4) HB_FMA(5, s5) HB_FMA(6, s6) HB_FMA(7, s7)
#undef HB_FMA
        }
        pb2[hh][0][e] = g0; pb2[hh][1][e] = g1; pb2[hh][2][e] = g2;
    }
    __syncthreads();

    // (3c) combine + squash; last iter writes out and exits (uniform)
    if (t < DIN) {
        float g0 = pb2[0][0][t] + pb2[1][0][t];
        float g1 = pb2[0][1][t] + pb2[1][1][t];
        float g2 = pb2[0][2][t] + pb2[1][2][t];
        float sq = g0 * g0 + g1 * g1 + g2 * g2;
        float scale = sq / (1.f + sq) / sqrtf(sq + 1e-9f);
        g0 *= scale; g1 *= scale; g2 *= scale;
        if (iter == 2) {
            size_t o = (size_t)b * 3 * DOUT + t;
            out[o] = g0; out[o + DOUT] = g1; out[o + 2 * DOUT] = g2;
        } else {
            sH[0][t] = g0; sH[1][t] = g1; sH[2][t] = g2;
        }
    }
    if (iter == 2) return;
    __syncthreads();

    // (4) hS = high @ S^T : d = t&127, hh = e-half; 8x8 named batches
    {
        const int d = t & 127, hh = t >> 7;
        const float* STcol = ST + d;
        float s0a = 0.f, s1a = 0.f, s2a = 0.f;
        for (int g = 0; g < 8; ++g) {
            const int eb = hh * 64 + g * 8;
            float s0 = STcol[(eb + 0) * DIN];
            float s1 = STcol[(eb + 1) * DIN];
            float s2 = STcol[(eb + 2) * DIN];
            float s3 = STcol[(eb + 3) * DIN];
            float s4 = STcol[(eb + 4) * DIN];
            float s5 = STcol[(eb + 5) * DIN];
            float s6 = STcol[(eb + 6) * DIN];
            float s7 = STcol[(eb + 7) * DIN];
#define HS_FMA(J, SV) \
            s0a = fmaf(sH[0][eb + J], SV, s0a); \
            s1a = fmaf(sH[1][eb + J], SV, s1a); \
            s2a = fmaf(sH[2][eb + J], SV, s2a);
            HS_FMA(0, s0) HS_FMA(1, s1) HS_FMA(2, s2) HS_FMA(3, s3)
            HS_FMA(4, s4) HS_FMA(5, s5) HS_FMA(6, s6) HS_FMA(7, s7)
#undef HS_FMA
        }
        pb2[hh][0][d] = s0a; pb2[hh][1][d] = s1a; pb2[hh][2][d] = s2a;
    }
    __syncthreads();
    if (t < DIN) {
        sHS[0][t] = pb2[0][0][t] + pb2[1][0][t];
        sHS[1][t] = pb2[0][1][t] + pb2[1][1][t];
        sHS[2][t] = pb2[0][2][t] + pb2[1][2][t];
    }
    __syncthreads();

    // (5) PC: B_delta[l] = hS . A[l]; thread = l reads its 512B row
    //     (8-deep float4 batches, A is L2/L3-hot from the WA pass).
    //     Then atomicAdd straight into accN (r11, proven; ~2.4MB traffic).
    if (t < SEQ) {
        const float* row = A + (size_t)b * (SEQ * DIN) + (size_t)t * DIN;
        float d0 = 0.f, d1 = 0.f, d2 = 0.f;
        for (int g = 0; g < 4; ++g) {
            const int jb = g * 8;
            float4 u0 = *(const float4*)&row[4 * (jb + 0)];
            float4 u1 = *(const float4*)&row[4 * (jb + 1)];
            float4 u2 = *(const float4*)&row[4 * (jb + 2)];
            float4 u3 = *(const float4*)&row[4 * (jb + 3)];
            float4 u4 = *(const float4*)&row[4 * (jb + 4)];
            float4 u5 = *(const float4*)&row[4 * (jb + 5)];
            float4 u6 = *(const float4*)&row[4 * (jb + 6)];
            float4 u7 = *(const float4*)&row[4 * (jb + 7)];
#define PC_FMA(J, U) { \
            float4 x0 = *(const float4*)&sHS[0][4 * (jb + J)]; \
            float4 x1 = *(const float4*)&sHS[1][4 * (jb + J)]; \
            float4 x2 = *(const float4*)&sHS[2][4 * (jb + J)]; \
            d0 += x0.x * U.x + x0.y * U.y + x0.z * U.z + x0.w * U.w; \
            d1 += x1.x * U.x + x1.y * U.y + x1.z * U.z + x1.w * U.w; \
            d2 += x2.x * U.x + x2.y * U.y + x2.z * U.z + x2.w * U.w; }
            PC_FMA(0, u0) PC_FMA(1, u1) PC_FMA(2, u2) PC_FMA(3, u3)
            PC_FMA(4, u4) PC_FMA(5, u5) PC_FMA(6, u6) PC_FMA(7, u7)
#undef PC_FMA
        }
        atomicAdd(&accN[t],       d0);
        atomicAdd(&accN[200 + t], d1);
        atomicAdd(&accN[400 + t], d2);
    }
}

extern "C" void kernel_launch(void* const* d_in, const int* in_sizes, int n_in,
                              void* d_out, int out_size, void* d_ws, size_t ws_size,
                              hipStream_t stream) {
    const float* low_capsule = (const float*)d_in[0];   // [1024][200][128]
    const float* B_matrix    = (const float*)d_in[1];   // [1][3][200]
    const float* S_matrix    = (const float*)d_in[2];   // [128][128]
    const int*   seq_len     = (const int*)d_in[3];     // [1024]
    float* out = (float*)d_out;                         // [1024][3][128]

    float* ST   = (float*)d_ws;          // 16384
    float* vL   = ST + 16384;            // 600  (+pad)
    float* Mn   = vL + 640;              // 603  (+pad)
    float* iEn  = Mn + 640;              // 603  (+pad)
    float* acc0 = iEn + 640;             // 600  (+pad)
    float* acc1 = acc0 + 640;            // 600  (+pad)

    k_transpose<<<64, 256, 0, stream>>>(S_matrix, ST, acc0, acc1);

    // iter 0
    k_scan<<<3, 256, 0, stream>>>(B_matrix, acc0, acc1, vL, Mn, iEn, 0);
    k_fused<<<BATCH, 256, 0, stream>>>(low_capsule, vL, Mn, iEn, seq_len,
                                       S_matrix, ST, acc0, out, 0);
    // iter 1
    k_scan<<<3, 256, 0, stream>>>(B_matrix, acc0, acc1, vL, Mn, iEn, 1);
    k_fused<<<BATCH, 256, 0, stream>>>(low_capsule, vL, Mn, iEn, seq_len,
                                       S_matrix, ST, acc1, out, 1);
    // iter 2 (no PC / no accumulation)
    k_scan<<<3, 256, 0, stream>>>(B_matrix, acc0, acc1, vL, Mn, iEn, 2);
    k_fused<<<BATCH, 256, 0, stream>>>(low_capsule, vL, Mn, iEn, seq_len,
                                       S_matrix, ST, acc1, out, 2);
}